// Round 6
// baseline (128.973 us; speedup 1.0000x reference)
//
#include <hip/hip_runtime.h>
#include <math.h>

// x: (512, 3, 32, 32) fp32
// layer1: C=3 -> F=32, R=16, 3x3  -> (512,32,30,30)
// layer2: C=32 -> F=32, R=16, 3x3 -> (512,32,28,28)
// classifier: 25088 -> 10, then log_softmax
//
// Algebraic fusion (h1, h2 never materialized):
//   M[r1][r2]       = sum_f l1_f0[f][r1] * l2_f3[f][r2]           (16x16)
//   Wc2L[n][h][r2][lr][c] = sum_f l2_f0[f][r2] * W_cls[n][f*784 + (h*14+lr)*28 + c]
// Wc2L is laid out to match t2's LDS order exactly -> stage 5 is linear.
//
// Structure: one block per image-HALF, NT=1024, __launch_bounds__(1024,8)
// (VGPR<=64 target; all stages designed with <=~25 live regs). LDS ~70 KB
// -> 2 blocks/CU = 32 waves/CU (max). Halves meet via atomicAdd of logit
// partials (2 commutative addends -> deterministic); LAST-arriving half
// block (per-image atomic counter) computes bias + log_softmax in-kernel.

#define NT 1024
#define S1S 34          // s1 row stride (floats): 8B-aligned, bank-decorrelated

__global__ void precomp_kernel(const float* __restrict__ l1_f0,
                               const float* __restrict__ l2_f0,
                               const float* __restrict__ l2_f3,
                               const float* __restrict__ Wcls,
                               float* __restrict__ Wc2L,
                               float* __restrict__ Mm,
                               float* __restrict__ Lg,
                               unsigned int* __restrict__ Cnt) {
    int id = blockIdx.x * blockDim.x + threadIdx.x;
    if (id < 7840) {                      // 10 classes x 784 pixels
        int n = id / 784;
        int pix = id - n * 784;
        int row = pix / 28;
        int col = pix - row * 28;
        int h = (row < 14) ? 0 : 1;
        int lr = row - h * 14;
        const float* wrow = &Wcls[n * 25088 + pix];
        float acc[16];
#pragma unroll
        for (int r2 = 0; r2 < 16; ++r2) acc[r2] = 0.f;
#pragma unroll
        for (int f = 0; f < 32; ++f) {
            float wv = wrow[f * 784];
#pragma unroll
            for (int r2 = 0; r2 < 16; ++r2)
                acc[r2] += l2_f0[f * 16 + r2] * wv;
        }
        float* dst = &Wc2L[n * 12544 + h * 6272 + lr * 28 + col];
#pragma unroll
        for (int r2 = 0; r2 < 16; ++r2)
            dst[r2 * 392] = acc[r2];
    }
    if (id < 256) {
        int r1 = id >> 4, r2 = id & 15;
        float acc = 0.f;
#pragma unroll
        for (int f = 0; f < 32; ++f)
            acc += l1_f0[f * 16 + r1] * l2_f3[f * 16 + r2];
        Mm[id] = acc;
    }
    if (id < 5120) Lg[id] = 0.f;
    if (id >= 5120 && id < 5632) Cnt[id - 5120] = 0u;
}

// Per-half geometry:
//   s1: 18 input rows (start h*14), stride S1S -> 16 x 18*S1S
//   t1/u: 16 rows x 30 cols (stride 480/rank)
//   t2: 14 rows x 28 cols  (stride 392/rank)
__global__ __launch_bounds__(NT, 8) void fused_half_kernel(
    const float* __restrict__ x,
    const float* __restrict__ l1_f1, const float* __restrict__ l1_f2,
    const float* __restrict__ l1_f3,
    const float* __restrict__ l2_f1, const float* __restrict__ l2_f2,
    const float* __restrict__ Wc2L, const float* __restrict__ Mm,
    const float* __restrict__ b_cls,
    float* __restrict__ Lg, unsigned int* __restrict__ Cnt,
    float* __restrict__ out) {
    __shared__ alignas(16) float sA[16 * 18 * S1S];  // s1, then u(16x480)  39.2KB
    __shared__ alignas(16) float sB[16 * 480];       // t1, then t2(16x392) 30.7KB
    __shared__ float sw1[144];
    __shared__ float sw2[144];
    __shared__ alignas(16) float sM[256];            // M [r1][r2]
    __shared__ float sred[16 * 10];
    __shared__ float slog[10];
    __shared__ int sflag;

    const int tid = threadIdx.x;
    const int b = blockIdx.x >> 1;
    const int h = blockIdx.x & 1;

    // ---- stage 0+1 (disjoint thread ranges, one barrier) ----
    if (tid < 144) {
        int r = tid / 9, ij = tid - r * 9;
        int i = ij / 3, j = ij - i * 3;
        sw1[tid] = l1_f1[i * 16 + r] * l1_f2[j * 16 + r];
    } else if (tid < 288) {
        int t = tid - 144;
        int r = t / 9, ij = t - r * 9;
        int i = ij / 3, j = ij - i * 3;
        sw2[t] = l2_f1[i * 16 + r] * l2_f2[j * 16 + r];
    } else if (tid < 544) {
        sM[tid - 288] = Mm[tid - 288];
    } else if (tid < 832) {
        // stage 1: s1[r][row][col] = sum_c x * f3; 288 threads x 2 px
        const int p = (tid - 544) * 2;         // 0..574, even
        const int row = p >> 5, col = p & 31;
        const int xbase = b * 3072 + h * 14 * 32 + p;
        float2 x0 = *(const float2*)&x[xbase];
        float2 x1 = *(const float2*)&x[xbase + 1024];
        float2 x2 = *(const float2*)&x[xbase + 2048];
        const int o = row * S1S + col;
#pragma unroll
        for (int r = 0; r < 16; ++r) {
            float f0 = l1_f3[r], f1 = l1_f3[16 + r], f2 = l1_f3[32 + r];
            *(float2*)&sA[r * (18 * S1S) + o] =
                make_float2(x0.x * f0 + x1.x * f1 + x2.x * f2,
                            x0.y * f0 + x1.y * f1 + x2.y * f2);
        }
    }
    __syncthreads();

    // ---- stage 2: t1[r] = conv3x3(s1[r]); 960 thr: (r, q=rowgroup, colpair), 4 rows ----
    if (tid < 960) {
        const int r = tid / 60;
        const int t = tid - r * 60;
        const int q = t / 15;
        const int pr = t - q * 15;
        const int c = 2 * pr;
        const int row0 = q * 4;
        const float* wp = &sw1[r * 9];
        const float w0 = wp[0], w1 = wp[1], w2 = wp[2];
        const float w3 = wp[3], w4 = wp[4], w5 = wp[5];
        const float w6 = wp[6], w7 = wp[7], w8 = wp[8];
        const float* base = &sA[r * (18 * S1S) + row0 * S1S + c];
        float2 aL = *(const float2*)&base[0];
        float2 aH = *(const float2*)&base[2];
        float2 bL = *(const float2*)&base[S1S];
        float2 bH = *(const float2*)&base[S1S + 2];
        float a0 = aL.x, a1 = aL.y, a2 = aH.x, a3 = aH.y;
        float b0 = bL.x, b1 = bL.y, b2 = bH.x, b3 = bH.y;
        float* op = &sB[r * 480 + row0 * 30 + c];
#pragma unroll
        for (int s = 0; s < 4; ++s) {
            const float* rp = base + (s + 2) * S1S;
            float2 cL = *(const float2*)&rp[0];
            float2 cH = *(const float2*)&rp[2];
            float o0 = w0 * a0 + w1 * a1 + w2 * a2
                     + w3 * b0 + w4 * b1 + w5 * b2
                     + w6 * cL.x + w7 * cL.y + w8 * cH.x;
            float o1 = w0 * a1 + w1 * a2 + w2 * a3
                     + w3 * b1 + w4 * b2 + w5 * b3
                     + w6 * cL.y + w7 * cH.x + w8 * cH.y;
            *(float2*)&op[s * 30] = make_float2(o0, o1);
            a0 = b0; a1 = b1; a2 = b2; a3 = b3;
            b0 = cL.x; b1 = cL.y; b2 = cH.x; b3 = cH.y;
        }
    }
    __syncthreads();

    // ---- stage 3: u[r2][p] = sum_r1 t1[r1][p]*M[r1][r2]; 960 thr: 2px x 4r2 ----
    if (tid < 960) {
        const int tr = tid & 3;
        const int tp = tid >> 2;          // 0..239
        const int p2 = tp * 2;
        const int r2b = tr * 4;
        float a00 = 0.f, a01 = 0.f;
        float a10 = 0.f, a11 = 0.f;
        float a20 = 0.f, a21 = 0.f;
        float a30 = 0.f, a31 = 0.f;
#pragma unroll
        for (int r1 = 0; r1 < 16; ++r1) {
            float2 tv = *(const float2*)&sB[r1 * 480 + p2];
            float4 mv = *(const float4*)&sM[r1 * 16 + r2b];
            a00 += mv.x * tv.x; a01 += mv.x * tv.y;
            a10 += mv.y * tv.x; a11 += mv.y * tv.y;
            a20 += mv.z * tv.x; a21 += mv.z * tv.y;
            a30 += mv.w * tv.x; a31 += mv.w * tv.y;
        }
        *(float2*)&sA[(r2b + 0) * 480 + p2] = make_float2(a00, a01);
        *(float2*)&sA[(r2b + 1) * 480 + p2] = make_float2(a10, a11);
        *(float2*)&sA[(r2b + 2) * 480 + p2] = make_float2(a20, a21);
        *(float2*)&sA[(r2b + 3) * 480 + p2] = make_float2(a30, a31);
    }
    __syncthreads();

    // ---- stage 4: t2[r2] = conv3x3(u[r2]); 896 thr: (r2, q, colpair), 4/4/3/3 rows ----
    if (tid < 896) {
        const int r2 = tid / 56;
        const int t = tid - r2 * 56;
        const int q = t / 14;
        const int pr = t - q * 14;
        const int c = 2 * pr;
        const int row0 = (q < 2) ? q * 4 : (8 + 3 * (q - 2));
        const int nrows = (q < 2) ? 4 : 3;
        const float* wp = &sw2[r2 * 9];
        const float w0 = wp[0], w1 = wp[1], w2 = wp[2];
        const float w3 = wp[3], w4 = wp[4], w5 = wp[5];
        const float w6 = wp[6], w7 = wp[7], w8 = wp[8];
        const float* base = &sA[r2 * 480 + row0 * 30 + c];
        float2 aL = *(const float2*)&base[0];
        float2 aH = *(const float2*)&base[2];
        float2 bL = *(const float2*)&base[30];
        float2 bH = *(const float2*)&base[32];
        float a0 = aL.x, a1 = aL.y, a2 = aH.x, a3 = aH.y;
        float b0 = bL.x, b1 = bL.y, b2 = bH.x, b3 = bH.y;
        float* op = &sB[r2 * 392 + row0 * 28 + c];
#pragma unroll
        for (int s = 0; s < 4; ++s) {
            if (s < nrows) {
                const float* rp = base + (s + 2) * 30;
                float2 cL = *(const float2*)&rp[0];
                float2 cH = *(const float2*)&rp[2];
                float o0 = w0 * a0 + w1 * a1 + w2 * a2
                         + w3 * b0 + w4 * b1 + w5 * b2
                         + w6 * cL.x + w7 * cL.y + w8 * cH.x;
                float o1 = w0 * a1 + w1 * a2 + w2 * a3
                         + w3 * b1 + w4 * b2 + w5 * b3
                         + w6 * cL.y + w7 * cH.x + w8 * cH.y;
                *(float2*)&op[s * 28] = make_float2(o0, o1);
                a0 = b0; a1 = b1; a2 = b2; a3 = b3;
                b0 = cL.x; b1 = cL.y; b2 = cH.x; b3 = cH.y;
            }
        }
    }
    __syncthreads();

    // ---- stage 5: partial logits; Wc2L is linear in sB's t2 order ----
    float acc[10];
#pragma unroll
    for (int n = 0; n < 10; ++n) acc[n] = 0.f;
    const float* wbase = &Wc2L[h * 6272];
    {
        // k = tid and k = tid + 1024 (1568 float4 chunks total)
        float4 tv = *(const float4*)&sB[tid * 4];
#pragma unroll
        for (int n = 0; n < 10; ++n) {
            float4 wv = *(const float4*)&wbase[n * 12544 + tid * 4];
            acc[n] += tv.x * wv.x + tv.y * wv.y + tv.z * wv.z + tv.w * wv.w;
        }
        if (tid < 544) {
            const int k = tid + 1024;
            float4 tv2 = *(const float4*)&sB[k * 4];
#pragma unroll
            for (int n = 0; n < 10; ++n) {
                float4 wv = *(const float4*)&wbase[n * 12544 + k * 4];
                acc[n] += tv2.x * wv.x + tv2.y * wv.y + tv2.z * wv.z + tv2.w * wv.w;
            }
        }
    }
#pragma unroll
    for (int n = 0; n < 10; ++n) {
        float v = acc[n];
#pragma unroll
        for (int off = 32; off > 0; off >>= 1)
            v += __shfl_down(v, off, 64);
        if ((tid & 63) == 0) sred[(tid >> 6) * 10 + n] = v;
    }
    __syncthreads();
    if (tid < 10) {
        float lg = 0.f;
#pragma unroll
        for (int w = 0; w < 16; ++w) lg += sred[w * 10 + tid];
        atomicAdd(&Lg[b * 10 + tid], lg);
    }
    // ---- last-arriving half computes bias + log_softmax ----
    if (tid == 0) {
        __threadfence();
        unsigned int old = atomicAdd(&Cnt[b], 1u);
        sflag = (old == 1u) ? 1 : 0;
    }
    __syncthreads();
    if (sflag) {
        if (tid < 10) {
            // atomic read-back: coherent across XCDs
            float v = atomicAdd(&Lg[b * 10 + tid], 0.0f) + b_cls[tid];
            slog[tid] = v;
        }
        __syncthreads();
        if (tid < 10) {
            float m = -1e30f;
#pragma unroll
            for (int n = 0; n < 10; ++n) m = fmaxf(m, slog[n]);
            float s = 0.f;
#pragma unroll
            for (int n = 0; n < 10; ++n) s += expf(slog[n] - m);
            out[b * 10 + tid] = slog[tid] - m - logf(s);
        }
    }
}

extern "C" void kernel_launch(void* const* d_in, const int* in_sizes, int n_in,
                              void* d_out, int out_size, void* d_ws, size_t ws_size,
                              hipStream_t stream) {
    const float* x     = (const float*)d_in[0];
    const float* l1_f0 = (const float*)d_in[1];
    const float* l1_f1 = (const float*)d_in[2];
    const float* l1_f2 = (const float*)d_in[3];
    const float* l1_f3 = (const float*)d_in[4];
    const float* l2_f0 = (const float*)d_in[5];
    const float* l2_f1 = (const float*)d_in[6];
    const float* l2_f2 = (const float*)d_in[7];
    const float* l2_f3 = (const float*)d_in[8];
    const float* Wcls  = (const float*)d_in[9];
    const float* bcls  = (const float*)d_in[10];
    float* out = (float*)d_out;

    float* Wc2L = (float*)d_ws;                    // 10*12544 floats
    float* Mm   = Wc2L + 10 * 12544;               // 256 floats
    float* Lg   = Mm + 256;                        // 5120 floats
    unsigned int* Cnt = (unsigned int*)(Lg + 5120);// 512 uints

    precomp_kernel<<<dim3(31), dim3(256), 0, stream>>>(
        l1_f0, l2_f0, l2_f3, Wcls, Wc2L, Mm, Lg, Cnt);
    fused_half_kernel<<<dim3(1024), dim3(NT), 0, stream>>>(
        x, l1_f1, l1_f2, l1_f3, l2_f1, l2_f2, Wc2L, Mm, bcls, Lg, Cnt, out);
}